// Round 7
// baseline (17482.887 us; speedup 1.0000x reference)
//
#include <hip/hip_runtime.h>
#include <stdint.h>

#define LSTEPS 2048
#define NB 32
#define IS 128
#define HS 1024
#define NGROUPS 8      // one per XCD (blockIdx % 8 round-robin)
#define WPG 32         // workgroups per group
#define BPG 4          // batch elements per group
#define CPW 32         // hidden columns per WG
#define NTHREADS 256
#define FLAG_SLOTS 8   // ring; flags zeroed each launch + exact-value match + skew<=1
#define FLAG_BYTES (NGROUPS * FLAG_SLOTS * WPG * 32 * 4)  // 256 KB

// flags layout (per-consumer replicated lines, verified in round 5):
//   dword index = ((g*FLAG_SLOTS + slot)*WPG + consumer)*32 + producer

__global__ __launch_bounds__(NTHREADS, 1)
void reservoir_scan(const float* __restrict__ x,
                    const float* __restrict__ h_init,
                    const float* __restrict__ W_in,
                    const float* __restrict__ bias,
                    const float* __restrict__ W_h,
                    float* __restrict__ out,
                    unsigned int* __restrict__ flags) {
  const int b    = blockIdx.x;
  const int g    = b & 7;     // group (likely = XCD)
  const int wg   = b >> 3;    // 0..31 within group
  const int tid  = threadIdx.x;
  const int w    = tid >> 6;  // wave 0..3  (owns 8 hidden cols)
  const int lane = tid & 63;  // k-split lane
  const int jbase = wg * CPW; // hidden-col base of this WG
  const int nbase = g * BPG;  // batch base of this group

  // LDS: only the resident W_h slice (128 KB). h goes global->register directly
  // via agent-scope atomic loads (the round-4/5-verified coherence path).
  __shared__ __align__(16) float wh_lds[CPW * HS];

  for (int e = tid * 4; e < CPW * HS; e += NTHREADS * 4)
    *(float4*)&wh_lds[e] = *(const float4*)&W_h[(size_t)jbase * HS + e];

  float2 wireg[8];
  #pragma unroll
  for (int jj = 0; jj < 8; ++jj)
    wireg[jj] = *(const float2*)&W_in[(size_t)(jbase + w * 8 + jj) * IS + lane * 2];

  // After the butterfly reduce, lane L holds output index i = L&31: nn = i>>3, jj = i&7.
  const int onn = (lane & 31) >> 3;
  const int ojj = lane & 7;
  const float my_bias = bias[jbase + w * 8 + ojj];

  __syncthreads();  // wh_lds visible before first compute

  #pragma unroll 1
  for (int t = 0; t < LSTEPS; ++t) {
    // ---- x(t) prefetch: input-only, independent of flags ----
    float2 xv[4];
    {
      const float* xsrc = x + (size_t)(t * NB + nbase) * IS;
      #pragma unroll
      for (int nn = 0; nn < 4; ++nn)
        xv[nn] = *(const float2*)&xsrc[nn * IS + lane * 2];
    }

    // ---- wait for all 32 producers of step t-1 (all waves poll own line) ----
    if (t > 0) {
      const unsigned int target = (unsigned int)t;  // value written for step t-1
      const unsigned int* fl =
          flags + (((size_t)(g * FLAG_SLOTS + ((t - 1) & (FLAG_SLOTS - 1))) * WPG + wg) << 5);
      int tries = 0;
      for (;;) {
        unsigned int v = (lane < WPG)
            ? __hip_atomic_load(&fl[lane], __ATOMIC_RELAXED, __HIP_MEMORY_SCOPE_AGENT)
            : target;
        if (__all(v == target)) break;
        // fail-fast bound: a legit wait is ~us; 2^18 polls ~ms. Converts any
        // protocol stall into a visible wrong-result instead of a container hang.
        if (++tries > (1 << 18)) break;
        if (tries > 3) __builtin_amdgcn_s_sleep(1);
      }
    }
    asm volatile("" ::: "memory");  // keep h loads below the detect

    // ---- h(t-1) direct global->register: 64 pipelined agent-scope loads/lane.
    //      Same coherence path as the verified rounds 4/5, minus the LDS bounce
    //      (deletes ds_write pass + barrier (b) + 16 ds_read_b128/lane).
    const float* hsrc = (t > 0) ? out + (size_t)((t - 1) * NB + nbase) * HS
                                : h_init + (size_t)nbase * HS;
    float hx[4][4][4];  // [u][nn][c], k = u*256 + lane*4 + c
    #pragma unroll
    for (int u = 0; u < 4; ++u)
      #pragma unroll
      for (int nn = 0; nn < 4; ++nn)
        #pragma unroll
        for (int c = 0; c < 4; ++c)
          hx[u][nn][c] = __hip_atomic_load(&hsrc[(size_t)nn * HS + u * 256 + lane * 4 + c],
                                           __ATOMIC_RELAXED, __HIP_MEMORY_SCOPE_AGENT);

    // ---- partial dot products: acc[jj][nn], k split across lanes ----
    float acc[8][4];
    #pragma unroll
    for (int jj = 0; jj < 8; ++jj)
      #pragma unroll
      for (int nn = 0; nn < 4; ++nn) acc[jj][nn] = 0.f;

    // input projection first: overlaps the in-flight h loads
    #pragma unroll
    for (int jj = 0; jj < 8; ++jj) {
      const float2 wv = wireg[jj];
      #pragma unroll
      for (int nn = 0; nn < 4; ++nn)
        acc[jj][nn] += wv.x * xv[nn].x + wv.y * xv[nn].y;
    }

    // recurrent part: k = u*256 + lane*4; W_h from LDS, h from registers
    #pragma unroll
    for (int u = 0; u < 4; ++u) {
      const int k = u * 256 + lane * 4;
      #pragma unroll
      for (int jj = 0; jj < 8; ++jj) {
        const float4 wv = *(const float4*)&wh_lds[(w * 8 + jj) * HS + k];
        #pragma unroll
        for (int nn = 0; nn < 4; ++nn) {
          acc[jj][nn] += wv.x * hx[u][nn][0];
          acc[jj][nn] += wv.y * hx[u][nn][1];
          acc[jj][nn] += wv.z * hx[u][nn][2];
          acc[jj][nn] += wv.w * hx[u][nn][3];
        }
      }
    }

    // ---- butterfly multi-value reduction: 32 values x 64 lanes -> lane L holds i = L&31 ----
    float a0[32];
    #pragma unroll
    for (int jj = 0; jj < 8; ++jj)
      #pragma unroll
      for (int nn = 0; nn < 4; ++nn)
        a0[nn * 8 + jj] = acc[jj][nn];

    float a1[16];
    {
      const int bit = lane & 1;
      #pragma unroll
      for (int q = 0; q < 16; ++q) {
        const float give = bit ? a0[2 * q] : a0[2 * q + 1];
        const float keep = bit ? a0[2 * q + 1] : a0[2 * q];
        a1[q] = keep + __shfl_xor(give, 1);
      }
    }
    float a2[8];
    {
      const int bit = (lane >> 1) & 1;
      #pragma unroll
      for (int q = 0; q < 8; ++q) {
        const float give = bit ? a1[2 * q] : a1[2 * q + 1];
        const float keep = bit ? a1[2 * q + 1] : a1[2 * q];
        a2[q] = keep + __shfl_xor(give, 2);
      }
    }
    float a3[4];
    {
      const int bit = (lane >> 2) & 1;
      #pragma unroll
      for (int q = 0; q < 4; ++q) {
        const float give = bit ? a2[2 * q] : a2[2 * q + 1];
        const float keep = bit ? a2[2 * q + 1] : a2[2 * q];
        a3[q] = keep + __shfl_xor(give, 4);
      }
    }
    float a4[2];
    {
      const int bit = (lane >> 3) & 1;
      #pragma unroll
      for (int q = 0; q < 2; ++q) {
        const float give = bit ? a3[2 * q] : a3[2 * q + 1];
        const float keep = bit ? a3[2 * q + 1] : a3[2 * q];
        a4[q] = keep + __shfl_xor(give, 8);
      }
    }
    float a5;
    {
      const int bit = (lane >> 4) & 1;
      const float give = bit ? a4[0] : a4[1];
      const float keep = bit ? a4[1] : a4[0];
      a5 = keep + __shfl_xor(give, 16);
    }
    const float r = a5 + __shfl_xor(a5, 32);  // full 64-lane sum of index lane&31

    if (lane < 32) {
      const float s = tanhf(r + my_bias);
      // d_out is both the result and the h-exchange medium.
      float* dst = out + (size_t)(t * NB + nbase + onn) * HS + (jbase + w * 8 + ojj);
      __hip_atomic_store(dst, s, __ATOMIC_RELAXED, __HIP_MEMORY_SCOPE_AGENT);
    }
    __syncthreads();  // single per-step barrier: drains all waves' stores before flags

    // ---- publish: one wave-store scatters this WG's flag into all 32 consumer lines ----
    if (tid < WPG) {
      unsigned int* fp =
          &flags[(((size_t)(g * FLAG_SLOTS + (t & (FLAG_SLOTS - 1))) * WPG + tid) << 5) + wg];
      __hip_atomic_store(fp, (unsigned int)(t + 1), __ATOMIC_RELEASE,
                         __HIP_MEMORY_SCOPE_AGENT);
    }
  }
}

extern "C" void kernel_launch(void* const* d_in, const int* in_sizes, int n_in,
                              void* d_out, int out_size, void* d_ws, size_t ws_size,
                              hipStream_t stream) {
  const float* x     = (const float*)d_in[0];
  const float* h0    = (const float*)d_in[1];
  const float* W_in  = (const float*)d_in[2];
  const float* bias  = (const float*)d_in[3];
  const float* W_h   = (const float*)d_in[4];
  float* out = (float*)d_out;
  unsigned int* flags = (unsigned int*)d_ws;

  // Zero the flag ring every launch (stream-ordered, graph-capture-safe: the
  // harness's own reset() enqueues hipMemsetAsync). Fixes the cross-launch
  // stale-flag tail race latent in rounds 5-6 (slot s retained value 2041+s,
  // matching steps 2041..2048 of the next launch -> unsynchronized free-run).
  hipMemsetAsync(flags, 0, FLAG_BYTES, stream);

  hipLaunchKernelGGL(reservoir_scan, dim3(NGROUPS * WPG), dim3(NTHREADS), 0, stream,
                     x, h0, W_in, bias, W_h, out, flags);
}